// Round 8
// baseline (397.530 us; speedup 1.0000x reference)
//
#include <hip/hip_runtime.h>

#define Bn 32
#define Nn 256
#define Hn 128
#define En 16
#define WWC 144
#define JT 8            // j-stripes (32 j)
#define IC 8            // i-chunks of 32 rows

typedef float v4 __attribute__((ext_vector_type(4)));
typedef int   i4 __attribute__((ext_vector_type(4)));

struct Flags {          // at ws start; memset to 0 each launch (4 KB region)
    int ecnt[256];      // per (b,jt) edge-producer count
    int zcq[256];       // per-column zero count
    int pcnt[32];       // per-b Ppart count
    int qdone[32];      // per-b Q ready flag
    int gate_done;      // -> 64
    int ut_done;        // -> 64
    int pad[62];
};

#define SH(j, m)  smemf[(j) * 132 + (m)]
#define SE(j, e)  smemf[4224 + (j) * 16 + (e)]
#define SQv(m)    smemf[4736 + (m)]
#define SWB(m)    smemf[4864 + (m)]
#define SCNT(j)   smemf[4992 + (j)]
#define SRB(m)    smemf[5024 + (m)]
#define SESUB(e)  smemf[5152 + (e)]

// ===== ONE kernel: producers + last-arriver consumers =====
// bid [0,64): gate+zcq; [64,320): Ppart (+last: P,Q); [320,384): U_T; [384,2432): edge (+last-per-group: final)
__global__ __launch_bounds__(256, 6) void k_all(
    const float* __restrict__ edge, const int* __restrict__ adj,
    const float* __restrict__ h, const float* __restrict__ U_w,
    const float* __restrict__ W_w, const float* __restrict__ W_b,
    const float* __restrict__ U_b, const int* __restrict__ num_nodes,
    Flags* fl, float* __restrict__ gate, float* __restrict__ Ppart,
    float* __restrict__ U_T, float* __restrict__ Q, float* __restrict__ epart,
    float* __restrict__ out)
{
    int bid = blockIdx.x, t = threadIdx.x;
    __shared__ __align__(16) float smemf[5168];
    __shared__ int sold;

    if (bid < 64) {
        // ---------- gate + zero-count ----------
        int f0 = bid * 1024;
        i4 s = {0, 0, 0, 0};
        #pragma unroll
        for (int b = 0; b < Bn; ++b)
            s += *reinterpret_cast<const i4*>(&adj[(size_t)b * (Nn * Nn) + f0 + t * 4]);
        v4 g;
        g[0] = s[0] > 0 ? 1.f : 0.f; g[1] = s[1] > 0 ? 1.f : 0.f;
        g[2] = s[2] > 0 ? 1.f : 0.f; g[3] = s[3] > 0 ? 1.f : 0.f;
        *reinterpret_cast<v4*>(&gate[f0 + t * 4]) = g;
        int* szl = reinterpret_cast<int*>(smemf);     // [4][256]
        int rr = t >> 6, c4 = (t & 63) * 4;
        szl[rr * 256 + c4 + 0] = (s[0] == 0);
        szl[rr * 256 + c4 + 1] = (s[1] == 0);
        szl[rr * 256 + c4 + 2] = (s[2] == 0);
        szl[rr * 256 + c4 + 3] = (s[3] == 0);
        __syncthreads();
        int zs = szl[t] + szl[256 + t] + szl[512 + t] + szl[768 + t];
        if (zs > 0) atomicAdd(&fl->zcq[t], zs);
        __threadfence();
        __syncthreads();
        if (t == 0) atomicAdd(&fl->gate_done, 1);
    } else if (bid < 320) {
        // ---------- Ppart; last block per b: P reduce + Q ----------
        int pb = bid - 64, b = pb >> 3, ic = pb & 7;
        int hh = t & 127, half = t >> 7;
        float s = 0.f;
        #pragma unroll
        for (int k = 0; k < 16; ++k)
            s += h[((size_t)b * Nn + ic * 32 + half * 16 + k) * Hn + hh];
        smemf[t] = s;
        __syncthreads();
        if (t < 128) Ppart[(ic * Bn + b) * Hn + t] = smemf[t] + smemf[t + 128];
        __threadfence();
        __syncthreads();
        if (t == 0) sold = atomicAdd(&fl->pcnt[b], 1);
        __syncthreads();
        if (sold == 7) {
            __threadfence();
            float* sP = smemf + 256;
            if (t < 128) {
                float p = 0.f;
                #pragma unroll
                for (int ic2 = 0; ic2 < IC; ++ic2) p += Ppart[(ic2 * Bn + b) * Hn + t];
                sP[t] = p;
            }
            __syncthreads();
            if (t < 128) {
                float q = 0.f;
                #pragma unroll 8
                for (int hh2 = 0; hh2 < Hn; ++hh2) q += W_w[t * WWC + hh2] * sP[hh2];
                Q[b * Hn + t] = q;
            }
            __threadfence();
            __syncthreads();
            if (t == 0)
                __hip_atomic_store(&fl->qdone[b], 1, __ATOMIC_RELEASE, __HIP_MEMORY_SCOPE_AGENT);
        }
    } else if (bid < 384) {
        // ---------- U_T ----------
        int m = (bid - 320) * 2 + (t >> 7), o = t & 127;
        U_T[m * Hn + o] = U_w[o * Hn + m];
        __threadfence();
        __syncthreads();
        if (t == 0) atomicAdd(&fl->ut_done, 1);
    } else {
        // ---------- edge stream; last block per (b,jt): final ----------
        int eb = bid - 384;
        int b = eb >> 6, r = eb & 63, ic = r >> 3, jt = r & 7;
        int g = b * JT + jt, j0 = jt * 32;
        int ig = t >> 7, vc = t & 127;
        v4* sred = reinterpret_cast<v4*>(smemf);
        const float* p = edge + ((size_t)b << 20) + (size_t)(ic * 32 + ig) * 4096 + jt * 512 + vc * 4;
        v4 a0 = {0.f,0.f,0.f,0.f}, a1 = a0, a2 = a0, a3 = a0;
        #pragma unroll
        for (int k = 0; k < 16; ++k) {
            v4 v = *reinterpret_cast<const v4*>(p + (size_t)k * 8192);
            if ((k & 3) == 0) a0 += v; else if ((k & 3) == 1) a1 += v;
            else if ((k & 3) == 2) a2 += v; else a3 += v;
        }
        v4 s = (a0 + a1) + (a2 + a3);
        if (ig == 1) sred[vc] = s;
        __syncthreads();
        if (ig == 0) {
            s += sred[vc];
            *reinterpret_cast<v4*>(&epart[(size_t)g * 4096 + ic * 512 + vc * 4]) = s;
        }
        __threadfence();
        __syncthreads();
        if (t == 0) sold = atomicAdd(&fl->ecnt[g], 1);
        __syncthreads();
        if (sold != 7) return;

        // ======== consumer: final GEMV for (b, columns j0..j0+31) ========
        // stage h tile sh[j][m] (overwrites sred region; safe post-sync)
        #pragma unroll
        for (int q = 0; q < 4; ++q) {
            int f = t + 256 * q, j = f >> 5, c = f & 31;
            *reinterpret_cast<v4*>(&SH(j, c * 4)) =
                *reinterpret_cast<const v4*>(&h[((size_t)b * Nn + j0 + j) * Hn + c * 4]);
        }
        if (t == 0) {
            while (__hip_atomic_load(&fl->gate_done, __ATOMIC_ACQUIRE, __HIP_MEMORY_SCOPE_AGENT) < 64)
                __builtin_amdgcn_s_sleep(4);
            while (__hip_atomic_load(&fl->ut_done, __ATOMIC_ACQUIRE, __HIP_MEMORY_SCOPE_AGENT) < 64)
                __builtin_amdgcn_s_sleep(4);
            while (__hip_atomic_load(&fl->qdone[b], __ATOMIC_ACQUIRE, __HIP_MEMORY_SCOPE_AGENT) == 0)
                __builtin_amdgcn_s_sleep(4);
        }
        __syncthreads();
        __threadfence();    // acquire: invalidate L1 before reading ws data

        if (t < 128) {      // E tile from epart (16 KB contiguous)
            const float* ep = epart + (size_t)g * 4096 + t * 4;
            v4 e = {0.f,0.f,0.f,0.f};
            #pragma unroll
            for (int ic2 = 0; ic2 < IC; ++ic2)
                e += *reinterpret_cast<const v4*>(ep + ic2 * 512);
            int j = t >> 2, e4 = (t & 3) * 4;
            *reinterpret_cast<v4*>(&SE(j, e4)) = e;
        } else {
            int m = t - 128;
            SQv(m) = Q[b * Hn + m];
            SWB(m) = W_b[m];
        }
        if (t < 32) SCNT(t) = (float)(Nn - fl->zcq[j0 + t]);
        __syncthreads();

        int nn = num_nodes[b];
        // rare exact corrections (gate zeros; p ~ 2^-32 per entry)
        for (int jj = 0; jj < 32; ++jj) {
            if (SCNT(jj) < 255.5f) {
                if (t < 128) {
                    float rr2 = 0.f;
                    for (int i = 0; i < Nn; ++i)
                        if (gate[i * Nn + j0 + jj] == 0.0f) rr2 += h[((size_t)b * Nn + i) * Hn + t];
                    SRB(t) = rr2;
                } else if (t < 144) {
                    int e = t - 128;
                    float rr2 = 0.f;
                    for (int i = 0; i < Nn; ++i)
                        if (gate[i * Nn + j0 + jj] == 0.0f)
                            rr2 += edge[(((size_t)b * Nn + i) * Nn + j0 + jj) * En + e];
                    SESUB(e) = rr2;
                }
                __syncthreads();
                if (t < 128 && (j0 + jj) < nn) {
                    float c = 0.f;
                    #pragma unroll 8
                    for (int hh = 0; hh < Hn; ++hh) c += W_w[t * WWC + hh] * SRB(hh);
                    #pragma unroll
                    for (int e = 0; e < En; ++e) c += W_w[t * WWC + Hn + e] * SESUB(e);
                    SH(jj, t) -= c;
                }
                __syncthreads();
            }
        }

        // fold y into sh: thread owns m = t&127, half of j range
        {
            int m = t & 127, jh = (t >> 7) * 16;
            const float* wp = &W_w[m * WWC + Hn];
            v4 w0 = *reinterpret_cast<const v4*>(wp);
            v4 w1 = *reinterpret_cast<const v4*>(wp + 4);
            v4 w2 = *reinterpret_cast<const v4*>(wp + 8);
            v4 w3 = *reinterpret_cast<const v4*>(wp + 12);
            float qm = SQv(m), wbm = SWB(m);
            for (int j = jh; j < jh + 16; ++j) {
                if (j0 + j < nn) {
                    v4 e0 = *reinterpret_cast<v4*>(&SE(j, 0));
                    v4 e1 = *reinterpret_cast<v4*>(&SE(j, 4));
                    v4 e2 = *reinterpret_cast<v4*>(&SE(j, 8));
                    v4 e3 = *reinterpret_cast<v4*>(&SE(j, 12));
                    v4 acc = w0 * e0 + w1 * e1 + w2 * e2 + w3 * e3;
                    SH(j, m) += qm + SCNT(j) * wbm + ((acc[0] + acc[1]) + (acc[2] + acc[3]));
                }
            }
        }
        __syncthreads();

        // GEMV: out[b, j0+j, o] = sum_m sh[j][m] * U_T[m][o] + U_b[o]
        int og = t & 31, o4 = og * 4, jq = t >> 5, j2 = jq * 4;
        v4 c0 = {0.f,0.f,0.f,0.f}, c1 = c0, c2 = c0, c3 = c0;
        #pragma unroll 8
        for (int m = 0; m < Hn; ++m) {
            v4 u = *reinterpret_cast<const v4*>(&U_T[m * Hn + o4]);
            c0 += SH(j2 + 0, m) * u;
            c1 += SH(j2 + 1, m) * u;
            c2 += SH(j2 + 2, m) * u;
            c3 += SH(j2 + 3, m) * u;
        }
        v4 ub = *reinterpret_cast<const v4*>(&U_b[o4]);
        size_t ob = ((size_t)b * Nn + j0 + j2) * Hn + o4;
        *reinterpret_cast<v4*>(&out[ob])           = c0 + ub;
        *reinterpret_cast<v4*>(&out[ob + Hn])      = c1 + ub;
        *reinterpret_cast<v4*>(&out[ob + 2 * Hn])  = c2 + ub;
        *reinterpret_cast<v4*>(&out[ob + 3 * Hn])  = c3 + ub;
    }
}

extern "C" void kernel_launch(void* const* d_in, const int* in_sizes, int n_in,
                              void* d_out, int out_size, void* d_ws, size_t ws_size,
                              hipStream_t stream) {
    const float* h    = (const float*)d_in[0];
    const float* edge = (const float*)d_in[1];
    const int*   adj  = (const int*)d_in[2];
    const int*   nn   = (const int*)d_in[3];
    const float* W_w  = (const float*)d_in[4];
    const float* W_b  = (const float*)d_in[5];
    const float* U_w  = (const float*)d_in[6];
    const float* U_b  = (const float*)d_in[7];
    float* out = (float*)d_out;

    float* ws    = (float*)d_ws;
    Flags* fl    = (Flags*)ws;            // 4 KB flags region
    float* gate  = ws + 1024;             // 65536 floats
    float* Ppart = ws + 1024 + 65536;     // 32768
    float* U_T   = ws + 1024 + 98304;     // 16384
    float* Q     = ws + 1024 + 114688;    // 4096
    float* epart = ws + 1024 + 118784;    // 1048576 (4 MB)

    hipMemsetAsync(fl, 0, 4096, stream);
    hipLaunchKernelGGL(k_all, dim3(2432), dim3(256), 0, stream,
                       edge, adj, h, U_w, W_w, W_b, U_b, nn,
                       fl, gate, Ppart, U_T, Q, epart, out);
}

// Round 9
// 46.959 us; speedup vs baseline: 8.4655x; 8.4655x over previous
//
#include <hip/hip_runtime.h>

#define Bn 32
#define Nn 256
#define Hn 128
#define En 16
#define WWC 144
#define JT 8            // j-stripes (32 j = 512 floats each)
#define IC 8            // i-chunks of 32 rows

typedef float v4 __attribute__((ext_vector_type(4)));
typedef int   i4 __attribute__((ext_vector_type(4)));

// ===== K1: all independent HBM-heavy + prep roles, ONE launch, edge first =====
// bid [0,2048): edge colsum partials; [2048,2112): gate + zpart; [2112,2368): Ppart; [2368,2432): U_T.
__global__ __launch_bounds__(256) void k_stream(const float* __restrict__ edge, const int* __restrict__ adj,
                                                const float* __restrict__ h, const float* __restrict__ U_w,
                                                float* __restrict__ epart, float* __restrict__ gate,
                                                float* __restrict__ Ppart, float* __restrict__ U_T,
                                                int* __restrict__ zpart) {
    int bid = blockIdx.x, t = threadIdx.x;
    if (bid < 2048) {
        // block (b, ic, jt): 32 rows (ic), 512-float j-stripe (jt). 64KB read, 2KB partial out.
        int b = bid >> 6, r = bid & 63, ic = r >> 3, jt = r & 7;
        int ig = t >> 7, vc = t & 127;
        __shared__ v4 sred[128];
        const float* p = edge + ((size_t)b << 20) + (size_t)(ic * 32 + ig) * 4096 + jt * 512 + vc * 4;
        v4 a0 = {0.f,0.f,0.f,0.f}, a1 = a0, a2 = a0, a3 = a0;
        #pragma unroll
        for (int k = 0; k < 16; ++k) {
            v4 v = *reinterpret_cast<const v4*>(p + (size_t)k * 8192);
            if ((k & 3) == 0) a0 += v; else if ((k & 3) == 1) a1 += v;
            else if ((k & 3) == 2) a2 += v; else a3 += v;
        }
        v4 s = (a0 + a1) + (a2 + a3);
        if (ig == 1) sred[vc] = s;
        __syncthreads();
        if (ig == 0) {
            s += sred[vc];
            *reinterpret_cast<v4*>(&epart[(((size_t)b * JT + jt) * IC + ic) * 512 + vc * 4]) = s;
        }
    } else if (bid < 2112) {
        // gate: 4 flattened i-rows per block; per-column zero partials -> zpart (no atomics)
        int g0 = bid - 2048, f0 = g0 * 1024;
        i4 s = {0, 0, 0, 0};
        #pragma unroll
        for (int b = 0; b < Bn; ++b)
            s += *reinterpret_cast<const i4*>(&adj[(size_t)b * (Nn * Nn) + f0 + t * 4]);
        v4 g;
        g[0] = s[0] > 0 ? 1.f : 0.f; g[1] = s[1] > 0 ? 1.f : 0.f;
        g[2] = s[2] > 0 ? 1.f : 0.f; g[3] = s[3] > 0 ? 1.f : 0.f;
        *reinterpret_cast<v4*>(&gate[f0 + t * 4]) = g;
        __shared__ int szl[4][Nn];
        int rr = t >> 6, c4 = (t & 63) * 4;
        szl[rr][c4 + 0] = (s[0] == 0);
        szl[rr][c4 + 1] = (s[1] == 0);
        szl[rr][c4 + 2] = (s[2] == 0);
        szl[rr][c4 + 3] = (s[3] == 0);
        __syncthreads();
        zpart[g0 * Nn + t] = szl[0][t] + szl[1][t] + szl[2][t] + szl[3][t];
    } else if (bid < 2368) {
        int pb = bid - 2112, b = pb >> 3, ic = pb & 7;
        int hh = t & 127, half = t >> 7;
        __shared__ float red[256];
        float s = 0.f;
        #pragma unroll
        for (int k = 0; k < 16; ++k)
            s += h[((size_t)b * Nn + ic * 32 + half * 16 + k) * Hn + hh];
        red[t] = s;
        __syncthreads();
        if (t < 128) Ppart[(ic * Bn + b) * Hn + t] = red[t] + red[t + 128];
    } else {
        int m = (bid - 2368) * 2 + (t >> 7), o = t & 127;
        U_T[m * Hn + o] = U_w[o * Hn + m];
    }
}

// ===== K2: everything dependent, fused. grid (JT, Bn) x 512 =====
__global__ __launch_bounds__(512) void k_final(
    const float* __restrict__ h, const float* __restrict__ U_T, const float* __restrict__ U_b,
    const float* __restrict__ W_w, const float* __restrict__ W_b, const float* __restrict__ gate,
    const float* __restrict__ Ppart, const float* __restrict__ epart, const float* __restrict__ edge,
    const int* __restrict__ zpart, const int* __restrict__ num_nodes, float* __restrict__ out) {
    int jt = blockIdx.x, j0 = jt * 32, b = blockIdx.y, t = threadIdx.x;
    __shared__ float shj[Hn][33];
    __shared__ float sWe[Hn][17];
    __shared__ float sE[32][17];
    __shared__ float sqp[Hn][4];
    __shared__ float sP[Hn], sQ[Hn], sWb[Hn], srbuf[Hn], sesub[En], scnt[32];
    __shared__ int szp[16][32];

    // ---- stage h tile (transposed) ----
    #pragma unroll
    for (int q = 0; q < 2; ++q) {
        int f = t + 512 * q, j = f >> 5, c = f & 31;
        v4 v = *reinterpret_cast<const v4*>(&h[((size_t)b * Nn + j0 + j) * Hn + c * 4]);
        shj[c * 4 + 0][j] = v[0];
        shj[c * 4 + 1][j] = v[1];
        shj[c * 4 + 2][j] = v[2];
        shj[c * 4 + 3][j] = v[3];
    }
    {   // We columns of W_w
        int m = t >> 2, c = t & 3;
        v4 v = *reinterpret_cast<const v4*>(&W_w[m * WWC + Hn + c * 4]);
        sWe[m][c * 4 + 0] = v[0];
        sWe[m][c * 4 + 1] = v[1];
        sWe[m][c * 4 + 2] = v[2];
        sWe[m][c * 4 + 3] = v[3];
    }
    {   // zero-count partial reduce: 16 groups x 32 cols, 4 blocks each
        int jj = t & 31, grp = t >> 5;
        int zp = 0;
        #pragma unroll
        for (int q = 0; q < 4; ++q) zp += zpart[(grp * 4 + q) * Nn + j0 + jj];
        szp[grp][jj] = zp;
    }
    if (t < 128) {          // E = reduce epart (contiguous 16KB per block)
        const float* ep = epart + (((size_t)b * JT + jt) * IC) * 512 + t * 4;
        v4 s = {0.f,0.f,0.f,0.f};
        #pragma unroll
        for (int ic = 0; ic < IC; ++ic)
            s += *reinterpret_cast<const v4*>(ep + ic * 512);
        int j = t >> 2, e4 = (t & 3) * 4;
        sE[j][e4 + 0] = s[0]; sE[j][e4 + 1] = s[1]; sE[j][e4 + 2] = s[2]; sE[j][e4 + 3] = s[3];
    } else if (t < 256) {   // P[b,:] = reduce Ppart
        int hh = t - 128;
        float p = 0.f;
        #pragma unroll
        for (int ic = 0; ic < IC; ++ic) p += Ppart[(ic * Bn + b) * Hn + hh];
        sP[hh] = p;
    } else if (t < 384) {
        sWb[t - 256] = W_b[t - 256];
    }
    __syncthreads();

    if (t < 32) {           // final zero counts
        int zc = 0;
        #pragma unroll
        for (int g2 = 0; g2 < 16; ++g2) zc += szp[g2][t];
        scnt[t] = (float)(Nn - zc);
    }
    {   // Q[b,m] = Wh[m,:]·P[b,:] : 4 threads per m
        int m = t >> 2, q = t & 3;
        const v4* wp = reinterpret_cast<const v4*>(&W_w[m * WWC + q * 32]);
        const v4* pp = reinterpret_cast<const v4*>(&sP[q * 32]);
        v4 sv = {0.f,0.f,0.f,0.f};
        #pragma unroll
        for (int k = 0; k < 8; ++k) sv += wp[k] * pp[k];
        sqp[m][q] = (sv[0] + sv[1]) + (sv[2] + sv[3]);
    }
    __syncthreads();
    if (t < 128) sQ[t] = (sqp[t][0] + sqp[t][1]) + (sqp[t][2] + sqp[t][3]);
    __syncthreads();

    int nn = num_nodes[b];
    // ---- rare exact corrections (gate zeros; normally never taken) ----
    for (int jj = 0; jj < 32; ++jj) {
        if (scnt[jj] < 255.5f) {
            if (t < 128) {
                float r = 0.f;
                for (int i = 0; i < Nn; ++i)
                    if (gate[i * Nn + j0 + jj] == 0.0f) r += h[((size_t)b * Nn + i) * Hn + t];
                srbuf[t] = r;
            } else if (t < 144) {
                int e = t - 128;
                float r = 0.f;
                for (int i = 0; i < Nn; ++i)
                    if (gate[i * Nn + j0 + jj] == 0.0f)
                        r += edge[(((size_t)b * Nn + i) * Nn + j0 + jj) * En + e];
                sesub[e] = r;
            }
            __syncthreads();
            if (t < 128 && (j0 + jj) < nn) {
                float c = 0.f;
                #pragma unroll 8
                for (int hh = 0; hh < Hn; ++hh) c += W_w[t * WWC + hh] * srbuf[hh];
                #pragma unroll
                for (int e = 0; e < En; ++e) c += sWe[t][e] * sesub[e];
                shj[t][jj] -= c;
            }
            __syncthreads();
        }
    }

    // ---- fold y into shj ----
    #pragma unroll
    for (int q = 0; q < 8; ++q) {
        int f = t + 512 * q, m = f >> 5, j = f & 31;
        if (j0 + j < nn) {
            float y = sQ[m] + scnt[j] * sWb[m];
            #pragma unroll
            for (int e = 0; e < En; ++e) y += sWe[m][e] * sE[j][e];
            shj[m][j] += y;
        }
    }
    __syncthreads();

    // ---- GEMV: out = z · U^T + U_b ----
    int og = t & 31, o4 = og * 4, jq = t >> 5, j2 = jq * 2;
    v4 acc0 = {0.f,0.f,0.f,0.f}, acc1 = acc0;
    #pragma unroll 8
    for (int m = 0; m < Hn; ++m) {
        v4 u = *reinterpret_cast<const v4*>(&U_T[m * Hn + o4]);
        acc0 += shj[m][j2] * u;
        acc1 += shj[m][j2 + 1] * u;
    }
    v4 ub = *reinterpret_cast<const v4*>(&U_b[o4]);
    *reinterpret_cast<v4*>(&out[((size_t)b * Nn + j0 + j2) * Hn + o4])     = acc0 + ub;
    *reinterpret_cast<v4*>(&out[((size_t)b * Nn + j0 + j2 + 1) * Hn + o4]) = acc1 + ub;
}

extern "C" void kernel_launch(void* const* d_in, const int* in_sizes, int n_in,
                              void* d_out, int out_size, void* d_ws, size_t ws_size,
                              hipStream_t stream) {
    const float* h    = (const float*)d_in[0];
    const float* edge = (const float*)d_in[1];
    const int*   adj  = (const int*)d_in[2];
    const int*   nn   = (const int*)d_in[3];
    const float* W_w  = (const float*)d_in[4];
    const float* W_b  = (const float*)d_in[5];
    const float* U_w  = (const float*)d_in[6];
    const float* U_b  = (const float*)d_in[7];
    float* out = (float*)d_out;

    float* ws    = (float*)d_ws;
    float* gate  = ws;                  // 65536 floats
    float* Ppart = ws + 65536;          // 32768
    float* U_T   = ws + 98304;          // 16384
    int*   zpart = (int*)(ws + 114688); // 64*256 = 16384 ints
    float* epart = ws + 131072;         // 1048576 floats (4MB)

    hipLaunchKernelGGL(k_stream, dim3(2432),   dim3(256), 0, stream,
                       edge, adj, h, U_w, epart, gate, Ppart, U_T, zpart);
    hipLaunchKernelGGL(k_final,  dim3(JT, Bn), dim3(512), 0, stream,
                       h, U_T, U_b, W_w, W_b, gate, Ppart, epart, edge, zpart, nn, out);
}